// Round 1
// baseline (965.612 us; speedup 1.0000x reference)
//
#include <hip/hip_runtime.h>

#define NROWS 262144   // 256*32*32
#define DDIM  64
#define KCODE 1024
#define GATHER_BLOCKS ((NROWS * 16) / 256)   // 16384
#define WINDOW 4e-3f   // certified: worst-case |approx_s - numpy_s| < 1.6e-3; 2.5x margin

// ---- ws layout (bytes) ----
// [0)        eT       float[KCODE*DDIM]   = 262144 B  (codebook transposed, [k][d])
// [262144)   norms    float[KCODE]        = 4096 B    (numpy-order sum of squares)
// [266240)   eh       ushort[KCODE*DDIM]  = 131072 B  (bf16 hi split of eT)
// [397312)   el       ushort[KCODE*DDIM]  = 131072 B  (bf16 lo split of eT)
// [528384)   idx      int[NROWS]          = 1 MiB     (bit31 = needs exact rescore)
// [1576960)  partials double[16384]       = 128 KiB
// [1708032)  cnt      int                 (compact-list counter, zeroed by vq_prep)
// [1709056)  list     int[NROWS]          = 1 MiB     (compacted flagged-row worklist)
//
// SEMANTICS (verified bit-exact rounds 2-4, absmax 0.0): oracle = numpy fp32,
// AVX512 pairwise sumsq, sequential-d fp32-FMA dot, dist = fl(fl(sumx+norm)-2dot),
// first-index argmin, out = fl(x + fl(q-x)). Exact path preserved in vq_prep /
// vq_rescore* / vq_gather. vq_filter is an APPROXIMATE pass with a certified
// error window; near-ties are rescored exactly. vq_rescore_c processes the SAME
// rows with the SAME per-(row,k) op order as vq_rescore — only scheduling
// (dense worklist + 4-way chain interleave) differs, so results are bit-identical.

typedef short bf16x8 __attribute__((ext_vector_type(8)));
typedef float f32x4  __attribute__((ext_vector_type(4)));

__device__ __forceinline__ unsigned short bf16_rne(float f) {
    unsigned u = __float_as_uint(f);
    unsigned r = u + 0x7fffu + ((u >> 16) & 1u);
    return (unsigned short)(r >> 16);
}

// ------------------------------------------------------------------
// P: transpose codebook, numpy-order norms, bf16 hi/lo splits, zero worklist cnt
__global__ __launch_bounds__(256) void vq_prep(const float* __restrict__ e,
                                               float* __restrict__ eT,
                                               float* __restrict__ norms,
                                               unsigned short* __restrict__ eh,
                                               unsigned short* __restrict__ el,
                                               int* cnt) {
#pragma clang fp contract(off)
    if (cnt && blockIdx.x == 0 && threadIdx.x == 0) *cnt = 0;
    const int k = blockIdx.x * 256 + threadIdx.x;   // 4 blocks x 256 = 1024
    float acc = 0.0f;
    for (int d = 0; d < DDIM; ++d) {
        float v = e[d * KCODE + k];      // e is [D][K]; coalesced across k-lanes
        eT[(k << 6) + d] = v;
        unsigned short h = bf16_rne(v);
        float hf = __uint_as_float((unsigned)h << 16);
        eh[(k << 6) + d] = h;
        el[(k << 6) + d] = bf16_rne(v - hf);   // Sterbenz: v-hf exact
        float sq = v * v;                // rounded square (numpy elementwise mul)
        acc = acc + sq;                  // sequential adds (numpy axis-0 reduce)
    }
    norms[k] = acc;
}

// ------------------------------------------------------------------
// numpy AVX512 pairwise sum of fl(x_d^2) — exact op order, do not touch
__device__ __forceinline__ float numpy_sumsq(const float* xr) {
#pragma clang fp contract(off)
    float u[16];
#pragma unroll
    for (int j = 0; j < 16; ++j) {
        float p0 = xr[j     ] * xr[j     ];
        float p1 = xr[j + 16] * xr[j + 16];
        float p2 = xr[j + 32] * xr[j + 32];
        float p3 = xr[j + 48] * xr[j + 48];
        u[j] = (p0 + p1) + (p2 + p3);
    }
    float v8[8];
#pragma unroll
    for (int j = 0; j < 8; ++j) v8[j] = u[j] + u[j + 8];
    float w4[4];
#pragma unroll
    for (int j = 0; j < 4; ++j) w4[j] = v8[j] + v8[j + 4];
    float y0 = w4[0] + w4[2];
    float y1 = w4[1] + w4[3];
    return y0 + y1;
}

// ------------------------------------------------------------------
// 1: MFMA split-bf16 approximate argmin. Wave = 64 rows x 1024 codes.
// s_k = norm_k - 2*dot_k (sumx is row-constant, irrelevant for argmin).
// Flags rows whose top-2 gap <= WINDOW for exact rescore (idx bit 31),
// and appends flagged rows to the compact worklist (cnt/list).
__global__ __launch_bounds__(256, 2) void vq_filter(const float* __restrict__ x,
                                                    const unsigned short* __restrict__ eh,
                                                    const unsigned short* __restrict__ el,
                                                    const float* __restrict__ norms,
                                                    int* __restrict__ idx,
                                                    int* cnt,
                                                    int* list) {
    const int lane = threadIdx.x & 63;
    const int wave = threadIdx.x >> 6;
    const int wavebase = blockIdx.x * 256 + wave * 64;   // 64 rows per wave
    const int m    = lane & 15;       // A-row within 16 / C-col (code) within 16
    const int quad = lane >> 4;       // k-chunk selector / C-row group

    // ---- build A fragments (hi/lo), 4 row-groups x 2 K-steps ----
    // A layout (verified m120): A[m=lane&15][k=quad*8+j]
    bf16x8 ah[4][2], al[4][2];
#pragma unroll
    for (int g = 0; g < 4; ++g) {
        const float* xp = x + (size_t)(wavebase + g * 16 + m) * DDIM + quad * 8;
#pragma unroll
        for (int s = 0; s < 2; ++s) {
            float4 v0 = *(const float4*)(xp + s * 32);
            float4 v1 = *(const float4*)(xp + s * 32 + 4);
            float f[8] = {v0.x, v0.y, v0.z, v0.w, v1.x, v1.y, v1.z, v1.w};
#pragma unroll
            for (int j = 0; j < 8; ++j) {
                unsigned short h = bf16_rne(f[j]);
                float hf = __uint_as_float((unsigned)h << 16);
                ah[g][s][j] = (short)h;
                al[g][s][j] = (short)bf16_rne(f[j] - hf);
            }
        }
    }

    // ---- per-lane running (min1, min2, argmin) for 4 groups x 4 C-rows ----
    float m1[4][4], m2[4][4];
    int   id[4][4];
#pragma unroll
    for (int g = 0; g < 4; ++g)
#pragma unroll
        for (int r = 0; r < 4; ++r) { m1[g][r] = 3.4e38f; m2[g][r] = 3.4e38f; id[g][r] = 0; }

    for (int tile = 0; tile < KCODE / 16; ++tile) {
        const int code = tile * 16 + m;
        // B layout: eT is B^T ([code][d]); lane loads B^T[n=lane&15][k=quad*8+j]
        const unsigned short* bp_h = eh + (code << 6) + quad * 8;
        const unsigned short* bp_l = el + (code << 6) + quad * 8;
        bf16x8 bh0 = *(const bf16x8*)(bp_h);
        bf16x8 bh1 = *(const bf16x8*)(bp_h + 32);
        bf16x8 bl0 = *(const bf16x8*)(bp_l);
        bf16x8 bl1 = *(const bf16x8*)(bp_l + 32);
        float nrm = norms[code];
#pragma unroll
        for (int g = 0; g < 4; ++g) {
            f32x4 acc = {0.f, 0.f, 0.f, 0.f};
            acc = __builtin_amdgcn_mfma_f32_16x16x32_bf16(ah[g][0], bh0, acc, 0, 0, 0);
            acc = __builtin_amdgcn_mfma_f32_16x16x32_bf16(ah[g][1], bh1, acc, 0, 0, 0);
            acc = __builtin_amdgcn_mfma_f32_16x16x32_bf16(ah[g][0], bl0, acc, 0, 0, 0);
            acc = __builtin_amdgcn_mfma_f32_16x16x32_bf16(ah[g][1], bl1, acc, 0, 0, 0);
            acc = __builtin_amdgcn_mfma_f32_16x16x32_bf16(al[g][0], bh0, acc, 0, 0, 0);
            acc = __builtin_amdgcn_mfma_f32_16x16x32_bf16(al[g][1], bh1, acc, 0, 0, 0);
            // C layout (verified m89/m91): col=lane&15 (code), row=quad*4+reg
#pragma unroll
            for (int r = 0; r < 4; ++r) {
                float sv = fmaf(-2.0f, acc[r], nrm);
                bool lt = sv < m1[g][r];
                m2[g][r] = lt ? m1[g][r] : fminf(m2[g][r], sv);
                m1[g][r] = lt ? sv : m1[g][r];
                id[g][r] = lt ? code : id[g][r];
            }
        }
    }

    // ---- cross-lane merge over the 16 code-columns (lanes sharing quad) ----
#pragma unroll
    for (int g = 0; g < 4; ++g)
#pragma unroll
        for (int r = 0; r < 4; ++r) {
            float a1 = m1[g][r], a2 = m2[g][r];
            int   ai = id[g][r];
            for (int mask = 1; mask < 16; mask <<= 1) {
                float o1 = __shfl_xor(a1, mask, 64);
                float o2 = __shfl_xor(a2, mask, 64);
                int   oi = __shfl_xor(ai, mask, 64);
                float n2 = fminf(fminf(a2, o2), fmaxf(a1, o1));
                bool take = o1 < a1;
                a1 = take ? o1 : a1;
                ai = take ? oi : ai;
                a2 = n2;
            }
            m1[g][r] = a1; m2[g][r] = a2; id[g][r] = ai;
        }

    if (m == 0) {
        // pass 1: write idx (flag bit31) and count this lane's flags
        int nf = 0;
#pragma unroll
        for (int g = 0; g < 4; ++g)
#pragma unroll
            for (int r = 0; r < 4; ++r) {
                int row = wavebase + g * 16 + quad * 4 + r;
                bool flag = (m2[g][r] - m1[g][r]) <= WINDOW;
                idx[row] = flag ? (id[g][r] | 0x80000000) : id[g][r];
                nf += flag ? 1 : 0;
            }
        // pass 2: one atomic per lane, append rows (no runtime-indexed local array)
        if (list && nf) {
            int base = atomicAdd(cnt, nf);
#pragma unroll
            for (int g = 0; g < 4; ++g)
#pragma unroll
                for (int r = 0; r < 4; ++r) {
                    int row = wavebase + g * 16 + quad * 4 + r;
                    bool flag = (m2[g][r] - m1[g][r]) <= WINDOW;
                    if (flag) list[base++] = row;
                }
        }
    }
}

// ------------------------------------------------------------------
// Rc: exact numpy rescore over the COMPACT worklist. One wave per row,
// grid-stride. 4 independent sequential-d FMA chains in flight per lane
// (each chain's op order identical to vq_rescore — bit-exact).
__global__ __launch_bounds__(256) void vq_rescore_c(const float* __restrict__ x,
                                                    const float* __restrict__ eT,
                                                    const float* __restrict__ norms,
                                                    int* __restrict__ idx,
                                                    const int* __restrict__ cnt,
                                                    const int* __restrict__ list) {
#pragma clang fp contract(off)
    const int lane = threadIdx.x & 63;
    const int wid  = (blockIdx.x * 256 + threadIdx.x) >> 6;
    const int nw   = (gridDim.x * 256) >> 6;
    const int total = *cnt;
    for (int w = wid; w < total; w += nw) {
        const int row = list[w];
        float xr[DDIM];
        const float4* xv = (const float4*)(x + (size_t)row * DDIM);
#pragma unroll
        for (int t = 0; t < DDIM / 4; ++t) {
            float4 v = xv[t];
            xr[4*t+0] = v.x; xr[4*t+1] = v.y; xr[4*t+2] = v.z; xr[4*t+3] = v.w;
        }
        float sumx = numpy_sumsq(xr);
        float best = 3.4e38f; int bi = 0;
        // k visit order per lane: ascending (jj*4+u)*64+lane — same order as the
        // original j=0..15 loop, so strict-< keeps the first index on ties.
#pragma unroll
        for (int jj = 0; jj < 4; ++jj) {
            const int k0 = ((jj * 4 + 0) << 6) + lane;
            const int k1 = k0 + 64, k2 = k0 + 128, k3 = k0 + 192;
            const float* __restrict__ e0 = eT + ((size_t)k0 << 6);
            const float* __restrict__ e1 = eT + ((size_t)k1 << 6);
            const float* __restrict__ e2 = eT + ((size_t)k2 << 6);
            const float* __restrict__ e3 = eT + ((size_t)k3 << 6);
            float a0 = 0.f, a1 = 0.f, a2 = 0.f, a3 = 0.f;
#pragma unroll
            for (int d = 0; d < DDIM; ++d) {
                float xd = xr[d];
                a0 = fmaf(xd, e0[d], a0);   // strict sequential d-chain per k
                a1 = fmaf(xd, e1[d], a1);
                a2 = fmaf(xd, e2[d], a2);
                a3 = fmaf(xd, e3[d], a3);
            }
            float t0 = sumx + norms[k0]; float d0 = t0 - 2.0f * a0;
            if (d0 < best) { best = d0; bi = k0; }
            float t1 = sumx + norms[k1]; float d1 = t1 - 2.0f * a1;
            if (d1 < best) { best = d1; bi = k1; }
            float t2 = sumx + norms[k2]; float d2 = t2 - 2.0f * a2;
            if (d2 < best) { best = d2; bi = k2; }
            float t3 = sumx + norms[k3]; float d3 = t3 - 2.0f * a3;
            if (d3 < best) { best = d3; bi = k3; }
        }
        // lexicographic (value, index) min across 64 lanes = first-index argmin
        for (int mask = 32; mask; mask >>= 1) {
            float ov = __shfl_xor(best, mask, 64);
            int   oi = __shfl_xor(bi,   mask, 64);
            if (ov < best || (ov == best && oi < bi)) { best = ov; bi = oi; }
        }
        if (lane == 0) idx[row] = bi;          // clears flag bit
    }
}

// ------------------------------------------------------------------
// R (fallback, only if ws too small for the worklist): exact numpy rescore
// of flagged rows. One wave per row. UNCHANGED from verified version.
__global__ __launch_bounds__(256) void vq_rescore(const float* __restrict__ x,
                                                  const float* __restrict__ eT,
                                                  const float* __restrict__ norms,
                                                  int* __restrict__ idx) {
#pragma clang fp contract(off)
    const int wave = threadIdx.x >> 6;
    const int lane = threadIdx.x & 63;
    const int rowbase = blockIdx.x * 16 + wave * 4;   // 16384 blocks x 16 rows
    for (int i = 0; i < 4; ++i) {
        const int row = rowbase + i;
        if (idx[row] >= 0) continue;           // uniform branch (broadcast load)
        float xr[DDIM];
        const float4* xv = (const float4*)(x + (size_t)row * DDIM);
#pragma unroll
        for (int t = 0; t < DDIM / 4; ++t) {
            float4 v = xv[t];
            xr[4*t+0] = v.x; xr[4*t+1] = v.y; xr[4*t+2] = v.z; xr[4*t+3] = v.w;
        }
        float sumx = numpy_sumsq(xr);
        float best = 3.4e38f; int bi = 0;
        for (int j = 0; j < 16; ++j) {
            const int k = j * 64 + lane;       // ascending k per lane
            const float* __restrict__ ek = eT + (k << 6);
            float a = 0.f;
#pragma unroll
            for (int d = 0; d < DDIM; ++d)
                a = fmaf(xr[d], ek[d], a);     // strict sequential d-chain
            float t0 = sumx + norms[k];
            float dist = t0 - 2.0f * a;        // fl(fl(sumx+norm) - 2*dot)
            if (dist < best) { best = dist; bi = k; }
        }
        // lexicographic (value, index) min across 64 lanes = first-index argmin
        for (int mask = 32; mask; mask >>= 1) {
            float ov = __shfl_xor(best, mask, 64);
            int   oi = __shfl_xor(bi,   mask, 64);
            if (ov < best || (ov == best && oi < bi)) { best = ov; bi = oi; }
        }
        if (lane == 0) idx[row] = bi;          // clears flag bit
    }
}

// ------------------------------------------------------------------
// 2: gather + straight-through + per-BLOCK loss partial (UNCHANGED, verified)
__global__ __launch_bounds__(256) void vq_gather(const float* __restrict__ x,
                                                 const float* __restrict__ eT,
                                                 const int* __restrict__ idx,
                                                 float* __restrict__ out,
                                                 double* __restrict__ partials) {
#pragma clang fp contract(off)
    __shared__ float wsum[4];
    const int t   = blockIdx.x * 256 + threadIdx.x;   // NROWS*16 threads
    const int row = t >> 4;
    const int j   = t & 15;
    const int k   = idx[row];
    float4 q  = ((const float4*)eT)[(k << 4) + j];
    float4 xv = ((const float4*)x)[t];
    float dx = q.x - xv.x, dy = q.y - xv.y, dz = q.z - xv.z, dw = q.w - xv.w;
    float4 o;
    o.x = xv.x + dx; o.y = xv.y + dy; o.z = xv.z + dz; o.w = xv.w + dw;
    ((float4*)out)[t] = o;
    float s = dx*dx + dy*dy + dz*dz + dw*dw;
#pragma unroll
    for (int off = 32; off > 0; off >>= 1) s += __shfl_down(s, off, 64);
    if ((threadIdx.x & 63) == 0) wsum[threadIdx.x >> 6] = s;
    __syncthreads();
    if (threadIdx.x == 0) {
        double b = (double)wsum[0] + (double)wsum[1]
                 + (double)wsum[2] + (double)wsum[3];
        partials[blockIdx.x] = b;
    }
}

// ------------------------------------------------------------------
// 3: reduce block partials; loss = 1.25 * mse (UNCHANGED, verified)
__global__ __launch_bounds__(256) void vq_finalize(const double* __restrict__ partials,
                                                   float* __restrict__ out_loss) {
    __shared__ double sd[256];
    double a = 0.0;
    for (int i = threadIdx.x; i < GATHER_BLOCKS; i += 256) a += partials[i];
    sd[threadIdx.x] = a;
    __syncthreads();
    for (int s = 128; s > 0; s >>= 1) {
        if (threadIdx.x < s) sd[threadIdx.x] += sd[threadIdx.x + s];
        __syncthreads();
    }
    if (threadIdx.x == 0) {
        double mse = sd[0] / (double)((size_t)NROWS * DDIM);
        *out_loss = (float)(1.25 * mse);
    }
}

// ------------------------------------------------------------------
extern "C" void kernel_launch(void* const* d_in, const int* in_sizes, int n_in,
                              void* d_out, int out_size, void* d_ws, size_t ws_size,
                              hipStream_t stream) {
    const float* x = (const float*)d_in[0];        // [N, 64]
    const float* e = (const float*)d_in[1];        // [64, 1024]
    float* out = (float*)d_out;                    // [N*64 quantized_st] + [1 loss]

    char* ws = (char*)d_ws;
    float*          eT       = (float*)(ws + 0);
    float*          norms    = (float*)(ws + 262144);
    unsigned short* eh       = (unsigned short*)(ws + 266240);
    unsigned short* el       = (unsigned short*)(ws + 397312);
    int*            idx      = (int*)(ws + 528384);
    double*         partials = (double*)(ws + 1576960);

    const size_t CNT_OFF  = 1708032;
    const size_t LIST_OFF = 1709056;
    const size_t REQUIRED = LIST_OFF + (size_t)NROWS * 4;   // ~2.63 MiB
    const bool compact = (ws_size >= REQUIRED);
    int* cnt  = compact ? (int*)(ws + CNT_OFF)  : (int*)0;
    int* list = compact ? (int*)(ws + LIST_OFF) : (int*)0;

    vq_prep    <<<KCODE / 256,   256, 0, stream>>>(e, eT, norms, eh, el, cnt);
    vq_filter  <<<NROWS / 256,   256, 0, stream>>>(x, eh, el, norms, idx, cnt, list);
    if (compact)
        vq_rescore_c<<<2048,     256, 0, stream>>>(x, eT, norms, idx, cnt, list);
    else
        vq_rescore  <<<NROWS/16, 256, 0, stream>>>(x, eT, norms, idx);
    vq_gather  <<<GATHER_BLOCKS, 256, 0, stream>>>(x, eT, idx, out, partials);
    vq_finalize<<<1,             256, 0, stream>>>(partials, out + (size_t)NROWS * DDIM);
}

// Round 2
// 695.765 us; speedup vs baseline: 1.3878x; 1.3878x over previous
//
#include <hip/hip_runtime.h>

#define NROWS 262144   // 256*32*32
#define DDIM  64
#define KCODE 1024
#define GATHER_BLOCKS ((NROWS * 16) / 256)   // 16384
#define WINDOW 4e-3f   // certified: worst-case |approx_s - numpy_s| < 1.6e-3; 2.5x margin

// ---- ws layout (bytes) ----
// [0)        eT       float[KCODE*DDIM]   = 262144 B  (codebook transposed, [k][d])
// [262144)   norms    float[KCODE]        = 4096 B    (numpy-order sum of squares)
// [266240)   eh       ushort[KCODE*DDIM]  = 131072 B  (bf16 hi split of eT)
// [397312)   el       ushort[KCODE*DDIM]  = 131072 B  (bf16 lo split of eT)
// [528384)   idx      int[NROWS]          = 1 MiB     (bit31 = needs exact rescore)
// [1576960)  partials double[16384]       = 128 KiB
// [1708032)  cnt      int                 (compact-list counter, zeroed by vq_prep)
// [1709056)  list     int[NROWS]          = 1 MiB     (compacted flagged-row worklist)
//
// SEMANTICS (verified bit-exact, absmax 0.0): oracle = numpy fp32,
// AVX512 pairwise sumsq, sequential-d fp32-FMA dot, dist = fl(fl(sumx+norm)-2dot),
// first-index argmin, out = fl(x + fl(q-x)). Exact path preserved in vq_prep /
// vq_rescore* / vq_gather. vq_filter is an APPROXIMATE pass with a certified
// error window; near-ties are rescored exactly.
//
// vq_rescore_c: SAME per-(row,k) op order as the verified vq_rescore — single
// sequential-d FMA chain per k, ascending k per lane — so results are
// bit-identical. Only two scheduling changes vs the verified baseline:
//   (a) rows come from the compacted worklist (every wave has work), and
//   (b) codebook reads go through e[d*K + k] (the ORIGINAL input layout, same
//       values as eT[k][d] by construction) so lanes are coalesced.
// ROUND-1 LESSON (counter-verified): the 4-chain ILP variant spilled
// (VGPR 256, 1.8 GB scratch traffic, 626 us). Do NOT add chain ILP here;
// the 48-VGPR single-chain codegen is the protected asset.

typedef short bf16x8 __attribute__((ext_vector_type(8)));
typedef float f32x4  __attribute__((ext_vector_type(4)));

__device__ __forceinline__ unsigned short bf16_rne(float f) {
    unsigned u = __float_as_uint(f);
    unsigned r = u + 0x7fffu + ((u >> 16) & 1u);
    return (unsigned short)(r >> 16);
}

// ------------------------------------------------------------------
// P: transpose codebook, numpy-order norms, bf16 hi/lo splits, zero worklist cnt
__global__ __launch_bounds__(256) void vq_prep(const float* __restrict__ e,
                                               float* __restrict__ eT,
                                               float* __restrict__ norms,
                                               unsigned short* __restrict__ eh,
                                               unsigned short* __restrict__ el,
                                               int* cnt) {
#pragma clang fp contract(off)
    if (cnt && blockIdx.x == 0 && threadIdx.x == 0) *cnt = 0;
    const int k = blockIdx.x * 256 + threadIdx.x;   // 4 blocks x 256 = 1024
    float acc = 0.0f;
    for (int d = 0; d < DDIM; ++d) {
        float v = e[d * KCODE + k];      // e is [D][K]; coalesced across k-lanes
        eT[(k << 6) + d] = v;
        unsigned short h = bf16_rne(v);
        float hf = __uint_as_float((unsigned)h << 16);
        eh[(k << 6) + d] = h;
        el[(k << 6) + d] = bf16_rne(v - hf);   // Sterbenz: v-hf exact
        float sq = v * v;                // rounded square (numpy elementwise mul)
        acc = acc + sq;                  // sequential adds (numpy axis-0 reduce)
    }
    norms[k] = acc;
}

// ------------------------------------------------------------------
// numpy AVX512 pairwise sum of fl(x_d^2) — exact op order, do not touch
__device__ __forceinline__ float numpy_sumsq(const float* xr) {
#pragma clang fp contract(off)
    float u[16];
#pragma unroll
    for (int j = 0; j < 16; ++j) {
        float p0 = xr[j     ] * xr[j     ];
        float p1 = xr[j + 16] * xr[j + 16];
        float p2 = xr[j + 32] * xr[j + 32];
        float p3 = xr[j + 48] * xr[j + 48];
        u[j] = (p0 + p1) + (p2 + p3);
    }
    float v8[8];
#pragma unroll
    for (int j = 0; j < 8; ++j) v8[j] = u[j] + u[j + 8];
    float w4[4];
#pragma unroll
    for (int j = 0; j < 4; ++j) w4[j] = v8[j] + v8[j + 4];
    float y0 = w4[0] + w4[2];
    float y1 = w4[1] + w4[3];
    return y0 + y1;
}

// ------------------------------------------------------------------
// 1: MFMA split-bf16 approximate argmin. Wave = 64 rows x 1024 codes.
// s_k = norm_k - 2*dot_k (sumx is row-constant, irrelevant for argmin).
// Flags rows whose top-2 gap <= WINDOW for exact rescore (idx bit 31),
// and appends flagged rows to the compact worklist (cnt/list).
__global__ __launch_bounds__(256, 2) void vq_filter(const float* __restrict__ x,
                                                    const unsigned short* __restrict__ eh,
                                                    const unsigned short* __restrict__ el,
                                                    const float* __restrict__ norms,
                                                    int* __restrict__ idx,
                                                    int* cnt,
                                                    int* list) {
    const int lane = threadIdx.x & 63;
    const int wave = threadIdx.x >> 6;
    const int wavebase = blockIdx.x * 256 + wave * 64;   // 64 rows per wave
    const int m    = lane & 15;       // A-row within 16 / C-col (code) within 16
    const int quad = lane >> 4;       // k-chunk selector / C-row group

    // ---- build A fragments (hi/lo), 4 row-groups x 2 K-steps ----
    // A layout (verified m120): A[m=lane&15][k=quad*8+j]
    bf16x8 ah[4][2], al[4][2];
#pragma unroll
    for (int g = 0; g < 4; ++g) {
        const float* xp = x + (size_t)(wavebase + g * 16 + m) * DDIM + quad * 8;
#pragma unroll
        for (int s = 0; s < 2; ++s) {
            float4 v0 = *(const float4*)(xp + s * 32);
            float4 v1 = *(const float4*)(xp + s * 32 + 4);
            float f[8] = {v0.x, v0.y, v0.z, v0.w, v1.x, v1.y, v1.z, v1.w};
#pragma unroll
            for (int j = 0; j < 8; ++j) {
                unsigned short h = bf16_rne(f[j]);
                float hf = __uint_as_float((unsigned)h << 16);
                ah[g][s][j] = (short)h;
                al[g][s][j] = (short)bf16_rne(f[j] - hf);
            }
        }
    }

    // ---- per-lane running (min1, min2, argmin) for 4 groups x 4 C-rows ----
    float m1[4][4], m2[4][4];
    int   id[4][4];
#pragma unroll
    for (int g = 0; g < 4; ++g)
#pragma unroll
        for (int r = 0; r < 4; ++r) { m1[g][r] = 3.4e38f; m2[g][r] = 3.4e38f; id[g][r] = 0; }

    for (int tile = 0; tile < KCODE / 16; ++tile) {
        const int code = tile * 16 + m;
        // B layout: eT is B^T ([code][d]); lane loads B^T[n=lane&15][k=quad*8+j]
        const unsigned short* bp_h = eh + (code << 6) + quad * 8;
        const unsigned short* bp_l = el + (code << 6) + quad * 8;
        bf16x8 bh0 = *(const bf16x8*)(bp_h);
        bf16x8 bh1 = *(const bf16x8*)(bp_h + 32);
        bf16x8 bl0 = *(const bf16x8*)(bp_l);
        bf16x8 bl1 = *(const bf16x8*)(bp_l + 32);
        float nrm = norms[code];
#pragma unroll
        for (int g = 0; g < 4; ++g) {
            f32x4 acc = {0.f, 0.f, 0.f, 0.f};
            acc = __builtin_amdgcn_mfma_f32_16x16x32_bf16(ah[g][0], bh0, acc, 0, 0, 0);
            acc = __builtin_amdgcn_mfma_f32_16x16x32_bf16(ah[g][1], bh1, acc, 0, 0, 0);
            acc = __builtin_amdgcn_mfma_f32_16x16x32_bf16(ah[g][0], bl0, acc, 0, 0, 0);
            acc = __builtin_amdgcn_mfma_f32_16x16x32_bf16(ah[g][1], bl1, acc, 0, 0, 0);
            acc = __builtin_amdgcn_mfma_f32_16x16x32_bf16(al[g][0], bh0, acc, 0, 0, 0);
            acc = __builtin_amdgcn_mfma_f32_16x16x32_bf16(al[g][1], bh1, acc, 0, 0, 0);
            // C layout (verified m89/m91): col=lane&15 (code), row=quad*4+reg
#pragma unroll
            for (int r = 0; r < 4; ++r) {
                float sv = fmaf(-2.0f, acc[r], nrm);
                bool lt = sv < m1[g][r];
                m2[g][r] = lt ? m1[g][r] : fminf(m2[g][r], sv);
                m1[g][r] = lt ? sv : m1[g][r];
                id[g][r] = lt ? code : id[g][r];
            }
        }
    }

    // ---- cross-lane merge over the 16 code-columns (lanes sharing quad) ----
#pragma unroll
    for (int g = 0; g < 4; ++g)
#pragma unroll
        for (int r = 0; r < 4; ++r) {
            float a1 = m1[g][r], a2 = m2[g][r];
            int   ai = id[g][r];
            for (int mask = 1; mask < 16; mask <<= 1) {
                float o1 = __shfl_xor(a1, mask, 64);
                float o2 = __shfl_xor(a2, mask, 64);
                int   oi = __shfl_xor(ai, mask, 64);
                float n2 = fminf(fminf(a2, o2), fmaxf(a1, o1));
                bool take = o1 < a1;
                a1 = take ? o1 : a1;
                ai = take ? oi : ai;
                a2 = n2;
            }
            m1[g][r] = a1; m2[g][r] = a2; id[g][r] = ai;
        }

    if (m == 0) {
        // pass 1: write idx (flag bit31) and count this lane's flags
        int nf = 0;
#pragma unroll
        for (int g = 0; g < 4; ++g)
#pragma unroll
            for (int r = 0; r < 4; ++r) {
                int row = wavebase + g * 16 + quad * 4 + r;
                bool flag = (m2[g][r] - m1[g][r]) <= WINDOW;
                idx[row] = flag ? (id[g][r] | 0x80000000) : id[g][r];
                nf += flag ? 1 : 0;
            }
        // pass 2: one atomic per lane, append rows (no runtime-indexed local array)
        if (list && nf) {
            int base = atomicAdd(cnt, nf);
#pragma unroll
            for (int g = 0; g < 4; ++g)
#pragma unroll
                for (int r = 0; r < 4; ++r) {
                    int row = wavebase + g * 16 + quad * 4 + r;
                    bool flag = (m2[g][r] - m1[g][r]) <= WINDOW;
                    if (flag) list[base++] = row;
                }
        }
    }
}

// ------------------------------------------------------------------
// Rc: exact numpy rescore over the COMPACT worklist. One wave per row,
// grid-stride. Inner structure IDENTICAL to the verified vq_rescore
// (single sequential-d chain, ascending k per lane). Codebook reads use
// the original e[d*K + k] layout: same values as eT[k][d] (vq_prep copies
// them), but consecutive lanes hit consecutive addresses -> coalesced.
__global__ __launch_bounds__(256) void vq_rescore_c(const float* __restrict__ x,
                                                    const float* __restrict__ e,
                                                    const float* __restrict__ norms,
                                                    int* __restrict__ idx,
                                                    const int* __restrict__ cnt,
                                                    const int* __restrict__ list) {
#pragma clang fp contract(off)
    const int lane = threadIdx.x & 63;
    const int wid  = (blockIdx.x * 256 + threadIdx.x) >> 6;
    const int nw   = (gridDim.x * 256) >> 6;
    const int total = *cnt;
    for (int w = wid; w < total; w += nw) {
        const int row = list[w];
        float xr[DDIM];
        const float4* xv = (const float4*)(x + (size_t)row * DDIM);
#pragma unroll
        for (int t = 0; t < DDIM / 4; ++t) {
            float4 v = xv[t];
            xr[4*t+0] = v.x; xr[4*t+1] = v.y; xr[4*t+2] = v.z; xr[4*t+3] = v.w;
        }
        float sumx = numpy_sumsq(xr);
        float best = 3.4e38f; int bi = 0;
        for (int j = 0; j < 16; ++j) {
            const int k = j * 64 + lane;       // ascending k per lane
            const float* __restrict__ ek = e + k;   // e[d][k]: lane-coalesced
            float a = 0.f;
#pragma unroll
            for (int d = 0; d < DDIM; ++d)
                a = fmaf(xr[d], ek[d * KCODE], a);  // strict sequential d-chain
            float t0 = sumx + norms[k];
            float dist = t0 - 2.0f * a;        // fl(fl(sumx+norm) - 2*dot)
            if (dist < best) { best = dist; bi = k; }
        }
        // lexicographic (value, index) min across 64 lanes = first-index argmin
        for (int mask = 32; mask; mask >>= 1) {
            float ov = __shfl_xor(best, mask, 64);
            int   oi = __shfl_xor(bi,   mask, 64);
            if (ov < best || (ov == best && oi < bi)) { best = ov; bi = oi; }
        }
        if (lane == 0) idx[row] = bi;          // clears flag bit
    }
}

// ------------------------------------------------------------------
// R (fallback, only if ws too small for the worklist): exact numpy rescore
// of flagged rows. One wave per row. UNCHANGED from verified version.
__global__ __launch_bounds__(256) void vq_rescore(const float* __restrict__ x,
                                                  const float* __restrict__ eT,
                                                  const float* __restrict__ norms,
                                                  int* __restrict__ idx) {
#pragma clang fp contract(off)
    const int wave = threadIdx.x >> 6;
    const int lane = threadIdx.x & 63;
    const int rowbase = blockIdx.x * 16 + wave * 4;   // 16384 blocks x 16 rows
    for (int i = 0; i < 4; ++i) {
        const int row = rowbase + i;
        if (idx[row] >= 0) continue;           // uniform branch (broadcast load)
        float xr[DDIM];
        const float4* xv = (const float4*)(x + (size_t)row * DDIM);
#pragma unroll
        for (int t = 0; t < DDIM / 4; ++t) {
            float4 v = xv[t];
            xr[4*t+0] = v.x; xr[4*t+1] = v.y; xr[4*t+2] = v.z; xr[4*t+3] = v.w;
        }
        float sumx = numpy_sumsq(xr);
        float best = 3.4e38f; int bi = 0;
        for (int j = 0; j < 16; ++j) {
            const int k = j * 64 + lane;       // ascending k per lane
            const float* __restrict__ ek = eT + (k << 6);
            float a = 0.f;
#pragma unroll
            for (int d = 0; d < DDIM; ++d)
                a = fmaf(xr[d], ek[d], a);     // strict sequential d-chain
            float t0 = sumx + norms[k];
            float dist = t0 - 2.0f * a;        // fl(fl(sumx+norm) - 2*dot)
            if (dist < best) { best = dist; bi = k; }
        }
        // lexicographic (value, index) min across 64 lanes = first-index argmin
        for (int mask = 32; mask; mask >>= 1) {
            float ov = __shfl_xor(best, mask, 64);
            int   oi = __shfl_xor(bi,   mask, 64);
            if (ov < best || (ov == best && oi < bi)) { best = ov; bi = oi; }
        }
        if (lane == 0) idx[row] = bi;          // clears flag bit
    }
}

// ------------------------------------------------------------------
// 2: gather + straight-through + per-BLOCK loss partial (UNCHANGED, verified)
__global__ __launch_bounds__(256) void vq_gather(const float* __restrict__ x,
                                                 const float* __restrict__ eT,
                                                 const int* __restrict__ idx,
                                                 float* __restrict__ out,
                                                 double* __restrict__ partials) {
#pragma clang fp contract(off)
    __shared__ float wsum[4];
    const int t   = blockIdx.x * 256 + threadIdx.x;   // NROWS*16 threads
    const int row = t >> 4;
    const int j   = t & 15;
    const int k   = idx[row];
    float4 q  = ((const float4*)eT)[(k << 4) + j];
    float4 xv = ((const float4*)x)[t];
    float dx = q.x - xv.x, dy = q.y - xv.y, dz = q.z - xv.z, dw = q.w - xv.w;
    float4 o;
    o.x = xv.x + dx; o.y = xv.y + dy; o.z = xv.z + dz; o.w = xv.w + dw;
    ((float4*)out)[t] = o;
    float s = dx*dx + dy*dy + dz*dz + dw*dw;
#pragma unroll
    for (int off = 32; off > 0; off >>= 1) s += __shfl_down(s, off, 64);
    if ((threadIdx.x & 63) == 0) wsum[threadIdx.x >> 6] = s;
    __syncthreads();
    if (threadIdx.x == 0) {
        double b = (double)wsum[0] + (double)wsum[1]
                 + (double)wsum[2] + (double)wsum[3];
        partials[blockIdx.x] = b;
    }
}

// ------------------------------------------------------------------
// 3: reduce block partials; loss = 1.25 * mse (UNCHANGED, verified)
__global__ __launch_bounds__(256) void vq_finalize(const double* __restrict__ partials,
                                                   float* __restrict__ out_loss) {
    __shared__ double sd[256];
    double a = 0.0;
    for (int i = threadIdx.x; i < GATHER_BLOCKS; i += 256) a += partials[i];
    sd[threadIdx.x] = a;
    __syncthreads();
    for (int s = 128; s > 0; s >>= 1) {
        if (threadIdx.x < s) sd[threadIdx.x] += sd[threadIdx.x + s];
        __syncthreads();
    }
    if (threadIdx.x == 0) {
        double mse = sd[0] / (double)((size_t)NROWS * DDIM);
        *out_loss = (float)(1.25 * mse);
    }
}

// ------------------------------------------------------------------
extern "C" void kernel_launch(void* const* d_in, const int* in_sizes, int n_in,
                              void* d_out, int out_size, void* d_ws, size_t ws_size,
                              hipStream_t stream) {
    const float* x = (const float*)d_in[0];        // [N, 64]
    const float* e = (const float*)d_in[1];        // [64, 1024]
    float* out = (float*)d_out;                    // [N*64 quantized_st] + [1 loss]

    char* ws = (char*)d_ws;
    float*          eT       = (float*)(ws + 0);
    float*          norms    = (float*)(ws + 262144);
    unsigned short* eh       = (unsigned short*)(ws + 266240);
    unsigned short* el       = (unsigned short*)(ws + 397312);
    int*            idx      = (int*)(ws + 528384);
    double*         partials = (double*)(ws + 1576960);

    const size_t CNT_OFF  = 1708032;
    const size_t LIST_OFF = 1709056;
    const size_t REQUIRED = LIST_OFF + (size_t)NROWS * 4;   // ~2.63 MiB
    const bool compact = (ws_size >= REQUIRED);
    int* cnt  = compact ? (int*)(ws + CNT_OFF)  : (int*)0;
    int* list = compact ? (int*)(ws + LIST_OFF) : (int*)0;

    vq_prep    <<<KCODE / 256,   256, 0, stream>>>(e, eT, norms, eh, el, cnt);
    vq_filter  <<<NROWS / 256,   256, 0, stream>>>(x, eh, el, norms, idx, cnt, list);
    if (compact)
        vq_rescore_c<<<4096,     256, 0, stream>>>(x, e, norms, idx, cnt, list);
    else
        vq_rescore  <<<NROWS/16, 256, 0, stream>>>(x, eT, norms, idx);
    vq_gather  <<<GATHER_BLOCKS, 256, 0, stream>>>(x, eT, idx, out, partials);
    vq_finalize<<<1,             256, 0, stream>>>(partials, out + (size_t)NROWS * DDIM);
}

// Round 3
// 384.333 us; speedup vs baseline: 2.5124x; 1.8103x over previous
//
#include <hip/hip_runtime.h>

#define NROWS 262144   // 256*32*32
#define DDIM  64
#define KCODE 1024
#define GATHER_BLOCKS ((NROWS * 16) / 256)   // 16384
#define WINDOW 4e-3f   // certified: worst-case |approx_s - numpy_s| < 1.6e-3; 2.5x margin

// ---- ws layout (bytes) ----
// [0)        eT       float[KCODE*DDIM]   = 262144 B  (codebook transposed, [k][d])
// [262144)   norms    float[KCODE]        = 4096 B    (numpy-order sum of squares)
// [266240)   eh       ushort[KCODE*DDIM]  = 131072 B  (bf16 hi split of eT)
// [397312)   el       ushort[KCODE*DDIM]  = 131072 B  (bf16 lo split of eT)
// [528384)   idx      int[NROWS]          = 1 MiB     (bit31 = needs exact rescore)
// [1576960)  partials double[16384]       = 128 KiB
// [1708032)  cnt      int                 (compact-list counter, zeroed by vq_prep)
// [1709056)  list     int[NROWS]          = 1 MiB     (compacted flagged-row worklist)
//
// SEMANTICS (verified bit-exact, absmax 0.0): oracle = numpy fp32,
// AVX512 pairwise sumsq, sequential-d fp32-FMA dot, dist = fl(fl(sumx+norm)-2dot),
// first-index argmin, out = fl(x + fl(q-x)). Exact path preserved in vq_prep /
// vq_rescore* / vq_gather. vq_filter is an APPROXIMATE pass with a certified
// error window; near-ties are rescored exactly.
//
// RESCORE HISTORY (counter-verified):
//  r0: one wave/row over sparse flags, eT[k][d] reads: 305 us (latency-bound).
//  r1: 4-chain ILP in one lane -> VGPR 256, 1.8 GB scratch spill, 626 us. BAD.
//  r2: compact worklist + e[d][k] reads, single chain: 348 us. 56 VGPR can't
//      hold a prefetch window -> 1024 loads/row serialized at ~300cy L2 latency.
//  r3 (this): vq_rescore_b — one BLOCK per 4 rows, thread t owns codes 4t..4t+3.
//      Per d: one dwordx4 e-load + LDS broadcast of x + 16 independent FMAs.
//      Chains are issue-bound (16-way ILP), regs ~45, codebook amortized x4.
//      Per-(row,k) op order IDENTICAL to vq_rescore -> bit-exact.

typedef short bf16x8 __attribute__((ext_vector_type(8)));
typedef float f32x4  __attribute__((ext_vector_type(4)));

__device__ __forceinline__ unsigned short bf16_rne(float f) {
    unsigned u = __float_as_uint(f);
    unsigned r = u + 0x7fffu + ((u >> 16) & 1u);
    return (unsigned short)(r >> 16);
}

// ------------------------------------------------------------------
// P: transpose codebook, numpy-order norms, bf16 hi/lo splits, zero worklist cnt
__global__ __launch_bounds__(256) void vq_prep(const float* __restrict__ e,
                                               float* __restrict__ eT,
                                               float* __restrict__ norms,
                                               unsigned short* __restrict__ eh,
                                               unsigned short* __restrict__ el,
                                               int* cnt) {
#pragma clang fp contract(off)
    if (cnt && blockIdx.x == 0 && threadIdx.x == 0) *cnt = 0;
    const int k = blockIdx.x * 256 + threadIdx.x;   // 4 blocks x 256 = 1024
    float acc = 0.0f;
    for (int d = 0; d < DDIM; ++d) {
        float v = e[d * KCODE + k];      // e is [D][K]; coalesced across k-lanes
        eT[(k << 6) + d] = v;
        unsigned short h = bf16_rne(v);
        float hf = __uint_as_float((unsigned)h << 16);
        eh[(k << 6) + d] = h;
        el[(k << 6) + d] = bf16_rne(v - hf);   // Sterbenz: v-hf exact
        float sq = v * v;                // rounded square (numpy elementwise mul)
        acc = acc + sq;                  // sequential adds (numpy axis-0 reduce)
    }
    norms[k] = acc;
}

// ------------------------------------------------------------------
// numpy AVX512 pairwise sum of fl(x_d^2) — exact op order, do not touch
__device__ __forceinline__ float numpy_sumsq(const float* xr) {
#pragma clang fp contract(off)
    float u[16];
#pragma unroll
    for (int j = 0; j < 16; ++j) {
        float p0 = xr[j     ] * xr[j     ];
        float p1 = xr[j + 16] * xr[j + 16];
        float p2 = xr[j + 32] * xr[j + 32];
        float p3 = xr[j + 48] * xr[j + 48];
        u[j] = (p0 + p1) + (p2 + p3);
    }
    float v8[8];
#pragma unroll
    for (int j = 0; j < 8; ++j) v8[j] = u[j] + u[j + 8];
    float w4[4];
#pragma unroll
    for (int j = 0; j < 4; ++j) w4[j] = v8[j] + v8[j + 4];
    float y0 = w4[0] + w4[2];
    float y1 = w4[1] + w4[3];
    return y0 + y1;
}

// ------------------------------------------------------------------
// 1: MFMA split-bf16 approximate argmin. Wave = 64 rows x 1024 codes.
// s_k = norm_k - 2*dot_k (sumx is row-constant, irrelevant for argmin).
// Flags rows whose top-2 gap <= WINDOW for exact rescore (idx bit 31),
// and appends flagged rows to the compact worklist (ONE atomic per wave).
__global__ __launch_bounds__(256, 2) void vq_filter(const float* __restrict__ x,
                                                    const unsigned short* __restrict__ eh,
                                                    const unsigned short* __restrict__ el,
                                                    const float* __restrict__ norms,
                                                    int* __restrict__ idx,
                                                    int* cnt,
                                                    int* list) {
    const int lane = threadIdx.x & 63;
    const int wave = threadIdx.x >> 6;
    const int wavebase = blockIdx.x * 256 + wave * 64;   // 64 rows per wave
    const int m    = lane & 15;       // A-row within 16 / C-col (code) within 16
    const int quad = lane >> 4;       // k-chunk selector / C-row group

    // ---- build A fragments (hi/lo), 4 row-groups x 2 K-steps ----
    // A layout (verified m120): A[m=lane&15][k=quad*8+j]
    bf16x8 ah[4][2], al[4][2];
#pragma unroll
    for (int g = 0; g < 4; ++g) {
        const float* xp = x + (size_t)(wavebase + g * 16 + m) * DDIM + quad * 8;
#pragma unroll
        for (int s = 0; s < 2; ++s) {
            float4 v0 = *(const float4*)(xp + s * 32);
            float4 v1 = *(const float4*)(xp + s * 32 + 4);
            float f[8] = {v0.x, v0.y, v0.z, v0.w, v1.x, v1.y, v1.z, v1.w};
#pragma unroll
            for (int j = 0; j < 8; ++j) {
                unsigned short h = bf16_rne(f[j]);
                float hf = __uint_as_float((unsigned)h << 16);
                ah[g][s][j] = (short)h;
                al[g][s][j] = (short)bf16_rne(f[j] - hf);
            }
        }
    }

    // ---- per-lane running (min1, min2, argmin) for 4 groups x 4 C-rows ----
    float m1[4][4], m2[4][4];
    int   id[4][4];
#pragma unroll
    for (int g = 0; g < 4; ++g)
#pragma unroll
        for (int r = 0; r < 4; ++r) { m1[g][r] = 3.4e38f; m2[g][r] = 3.4e38f; id[g][r] = 0; }

    for (int tile = 0; tile < KCODE / 16; ++tile) {
        const int code = tile * 16 + m;
        // B layout: eT is B^T ([code][d]); lane loads B^T[n=lane&15][k=quad*8+j]
        const unsigned short* bp_h = eh + (code << 6) + quad * 8;
        const unsigned short* bp_l = el + (code << 6) + quad * 8;
        bf16x8 bh0 = *(const bf16x8*)(bp_h);
        bf16x8 bh1 = *(const bf16x8*)(bp_h + 32);
        bf16x8 bl0 = *(const bf16x8*)(bp_l);
        bf16x8 bl1 = *(const bf16x8*)(bp_l + 32);
        float nrm = norms[code];
#pragma unroll
        for (int g = 0; g < 4; ++g) {
            f32x4 acc = {0.f, 0.f, 0.f, 0.f};
            acc = __builtin_amdgcn_mfma_f32_16x16x32_bf16(ah[g][0], bh0, acc, 0, 0, 0);
            acc = __builtin_amdgcn_mfma_f32_16x16x32_bf16(ah[g][1], bh1, acc, 0, 0, 0);
            acc = __builtin_amdgcn_mfma_f32_16x16x32_bf16(ah[g][0], bl0, acc, 0, 0, 0);
            acc = __builtin_amdgcn_mfma_f32_16x16x32_bf16(ah[g][1], bl1, acc, 0, 0, 0);
            acc = __builtin_amdgcn_mfma_f32_16x16x32_bf16(al[g][0], bh0, acc, 0, 0, 0);
            acc = __builtin_amdgcn_mfma_f32_16x16x32_bf16(al[g][1], bh1, acc, 0, 0, 0);
            // C layout (verified m89/m91): col=lane&15 (code), row=quad*4+reg
#pragma unroll
            for (int r = 0; r < 4; ++r) {
                float sv = fmaf(-2.0f, acc[r], nrm);
                bool lt = sv < m1[g][r];
                m2[g][r] = lt ? m1[g][r] : fminf(m2[g][r], sv);
                m1[g][r] = lt ? sv : m1[g][r];
                id[g][r] = lt ? code : id[g][r];
            }
        }
    }

    // ---- cross-lane merge over the 16 code-columns (lanes sharing quad) ----
#pragma unroll
    for (int g = 0; g < 4; ++g)
#pragma unroll
        for (int r = 0; r < 4; ++r) {
            float a1 = m1[g][r], a2 = m2[g][r];
            int   ai = id[g][r];
            for (int mask = 1; mask < 16; mask <<= 1) {
                float o1 = __shfl_xor(a1, mask, 64);
                float o2 = __shfl_xor(a2, mask, 64);
                int   oi = __shfl_xor(ai, mask, 64);
                float n2 = fminf(fminf(a2, o2), fmaxf(a1, o1));
                bool take = o1 < a1;
                a1 = take ? o1 : a1;
                ai = take ? oi : ai;
                a2 = n2;
            }
            m1[g][r] = a1; m2[g][r] = a2; id[g][r] = ai;
        }

    // After the merge, m1/m2/id are uniform across the 16 lanes of each quad,
    // so EVERY lane can compute its quad's flag count (no divergence here).
    int nf = 0;
#pragma unroll
    for (int g = 0; g < 4; ++g)
#pragma unroll
        for (int r = 0; r < 4; ++r)
            nf += ((m2[g][r] - m1[g][r]) <= WINDOW) ? 1 : 0;

    // wave-aggregated worklist append: ONE atomic per wave
    int myoff = 0;
    if (list) {
        int nf0 = __shfl(nf, 0, 64);
        int nf1 = __shfl(nf, 16, 64);
        int nf2 = __shfl(nf, 32, 64);
        int nf3 = __shfl(nf, 48, 64);
        int wtotal = nf0 + nf1 + nf2 + nf3;
        int wbase = 0;
        if (lane == 0 && wtotal) wbase = atomicAdd(cnt, wtotal);
        wbase = __shfl(wbase, 0, 64);
        myoff = wbase + (quad > 0 ? nf0 : 0) + (quad > 1 ? nf1 : 0)
                      + (quad > 2 ? nf2 : 0);
    }

    if (m == 0) {
#pragma unroll
        for (int g = 0; g < 4; ++g)
#pragma unroll
            for (int r = 0; r < 4; ++r) {
                int row = wavebase + g * 16 + quad * 4 + r;
                bool flag = (m2[g][r] - m1[g][r]) <= WINDOW;
                idx[row] = flag ? (id[g][r] | 0x80000000) : id[g][r];
                if (list && flag) list[myoff++] = row;
            }
    }
}

// ------------------------------------------------------------------
// Rb: exact numpy rescore, one BLOCK per group of 4 worklist rows.
// Thread t owns codes k = 4t..4t+3 (ascending within thread; lexicographic
// (value,index) reduction across threads => global first-index argmin).
// Per d-step: one dwordx4 load of e[d][4t..4t+3] (wave reads a contiguous
// 1 KiB slice -> fully coalesced) + LDS broadcast of xs[r][d] + 16 chained
// FMAs (4 rows x 4 codes, independent chains -> issue-bound, latency hidden).
// Each chain's op order is IDENTICAL to vq_rescore: bit-exact.
__global__ __launch_bounds__(256) void vq_rescore_b(const float* __restrict__ x,
                                                    const float* __restrict__ e,   // [D][K]
                                                    const float* __restrict__ norms,
                                                    int* __restrict__ idx,
                                                    const int* __restrict__ cnt,
                                                    const int* __restrict__ list) {
#pragma clang fp contract(off)
    __shared__ float xs[4][DDIM];     // 4 staged rows
    __shared__ float sumxs[4];
    __shared__ int   rows_s[4];
    __shared__ float wval[4][4];      // [row][wave] lex-reduce partials
    __shared__ int   widx[4][4];

    const int tid  = threadIdx.x;
    const int lane = tid & 63;
    const int wave = tid >> 6;
    const int total = *cnt;
    const int ngroups = (total + 3) >> 2;

    const float* ep = e + (tid << 2);                       // e[0][4t]
    const float4 nv = *(const float4*)(norms + (tid << 2)); // norms[4t..4t+3]

    for (int g = blockIdx.x; g < ngroups; g += gridDim.x) {
        const int base = g * 4;
        const int nr = min(4, total - base);

        // ---- stage 4 rows into LDS (64 threads per row, stride-1: no conflicts)
        {
            int r = wave;            // tid>>6: one wave per row
            int d = lane;
            int row = (r < nr) ? list[base + r] : list[base];  // pad with row 0
            if (d == 0) rows_s[r] = row;
            xs[r][d] = x[(size_t)row * DDIM + d];
        }
        __syncthreads();

        // ---- sumsq per row: wave r computes row r with a bit-exact 16-lane tree.
        // u[j] on lane j (j<16); each xor level adds self+other, reproducing
        // numpy's pairwise order exactly (IEEE add is bitwise commutative).
        {
            int r = wave;
            float uj = 0.f;
            if (lane < 16) {
                float a0 = xs[r][lane];
                float a1 = xs[r][lane + 16];
                float a2 = xs[r][lane + 32];
                float a3 = xs[r][lane + 48];
                float p0 = a0 * a0, p1 = a1 * a1, p2 = a2 * a2, p3 = a3 * a3;
                uj = (p0 + p1) + (p2 + p3);
            }
            uj = uj + __shfl_xor(uj, 8, 64);   // v8[j] = u[j] + u[j+8]
            uj = uj + __shfl_xor(uj, 4, 64);   // w4[j] = v8[j] + v8[j+4]
            uj = uj + __shfl_xor(uj, 2, 64);   // y0 = w4[0]+w4[2] (lane0)
            uj = uj + __shfl_xor(uj, 1, 64);   // y0+y1 (lane0)
            if (lane == 0) sumxs[r] = uj;
        }
        __syncthreads();

        // ---- 16 independent sequential-d chains: 4 rows x 4 codes ----
        f32x4 a0 = {0.f, 0.f, 0.f, 0.f};
        f32x4 a1 = {0.f, 0.f, 0.f, 0.f};
        f32x4 a2 = {0.f, 0.f, 0.f, 0.f};
        f32x4 a3 = {0.f, 0.f, 0.f, 0.f};
#pragma unroll 8
        for (int d = 0; d < DDIM; ++d) {
            float4 ev = *(const float4*)(ep + (size_t)d * KCODE);
            float x0 = xs[0][d], x1 = xs[1][d], x2 = xs[2][d], x3 = xs[3][d];
            a0.x = fmaf(x0, ev.x, a0.x); a0.y = fmaf(x0, ev.y, a0.y);
            a0.z = fmaf(x0, ev.z, a0.z); a0.w = fmaf(x0, ev.w, a0.w);
            a1.x = fmaf(x1, ev.x, a1.x); a1.y = fmaf(x1, ev.y, a1.y);
            a1.z = fmaf(x1, ev.z, a1.z); a1.w = fmaf(x1, ev.w, a1.w);
            a2.x = fmaf(x2, ev.x, a2.x); a2.y = fmaf(x2, ev.y, a2.y);
            a2.z = fmaf(x2, ev.z, a2.z); a2.w = fmaf(x2, ev.w, a2.w);
            a3.x = fmaf(x3, ev.x, a3.x); a3.y = fmaf(x3, ev.y, a3.y);
            a3.z = fmaf(x3, ev.z, a3.z); a3.w = fmaf(x3, ev.w, a3.w);
        }

        // ---- per-row distances + lexicographic first-index argmin ----
#pragma unroll
        for (int r = 0; r < 4; ++r) {
            f32x4 ar = (r == 0) ? a0 : (r == 1) ? a1 : (r == 2) ? a2 : a3;
            float sx = sumxs[r];
            float bv = 3.4e38f; int bx = 0;
            {   // ascending k within thread: first-index on ties via strict <
                float t0 = sx + nv.x; float d0 = t0 - 2.0f * ar.x;
                if (d0 < bv) { bv = d0; bx = (tid << 2) + 0; }
                float t1 = sx + nv.y; float d1 = t1 - 2.0f * ar.y;
                if (d1 < bv) { bv = d1; bx = (tid << 2) + 1; }
                float t2 = sx + nv.z; float d2 = t2 - 2.0f * ar.z;
                if (d2 < bv) { bv = d2; bx = (tid << 2) + 2; }
                float t3 = sx + nv.w; float d3 = t3 - 2.0f * ar.w;
                if (d3 < bv) { bv = d3; bx = (tid << 2) + 3; }
            }
            for (int mask = 32; mask; mask >>= 1) {
                float ov = __shfl_xor(bv, mask, 64);
                int   ox = __shfl_xor(bx, mask, 64);
                if (ov < bv || (ov == bv && ox < bx)) { bv = ov; bx = ox; }
            }
            if (lane == 0) { wval[r][wave] = bv; widx[r][wave] = bx; }
        }
        __syncthreads();

        if (tid < nr) {
            float bv = wval[tid][0]; int bx = widx[tid][0];
#pragma unroll
            for (int w = 1; w < 4; ++w) {
                float ov = wval[tid][w]; int ox = widx[tid][w];
                if (ov < bv || (ov == bv && ox < bx)) { bv = ov; bx = ox; }
            }
            idx[rows_s[tid]] = bx;    // clears flag bit
        }
        __syncthreads();   // protect xs/rows_s/wval before next group
    }
}

// ------------------------------------------------------------------
// R (fallback, only if ws too small for the worklist): exact numpy rescore
// of flagged rows. One wave per row. UNCHANGED from verified version.
__global__ __launch_bounds__(256) void vq_rescore(const float* __restrict__ x,
                                                  const float* __restrict__ eT,
                                                  const float* __restrict__ norms,
                                                  int* __restrict__ idx) {
#pragma clang fp contract(off)
    const int wave = threadIdx.x >> 6;
    const int lane = threadIdx.x & 63;
    const int rowbase = blockIdx.x * 16 + wave * 4;   // 16384 blocks x 16 rows
    for (int i = 0; i < 4; ++i) {
        const int row = rowbase + i;
        if (idx[row] >= 0) continue;           // uniform branch (broadcast load)
        float xr[DDIM];
        const float4* xv = (const float4*)(x + (size_t)row * DDIM);
#pragma unroll
        for (int t = 0; t < DDIM / 4; ++t) {
            float4 v = xv[t];
            xr[4*t+0] = v.x; xr[4*t+1] = v.y; xr[4*t+2] = v.z; xr[4*t+3] = v.w;
        }
        float sumx = numpy_sumsq(xr);
        float best = 3.4e38f; int bi = 0;
        for (int j = 0; j < 16; ++j) {
            const int k = j * 64 + lane;       // ascending k per lane
            const float* __restrict__ ek = eT + (k << 6);
            float a = 0.f;
#pragma unroll
            for (int d = 0; d < DDIM; ++d)
                a = fmaf(xr[d], ek[d], a);     // strict sequential d-chain
            float t0 = sumx + norms[k];
            float dist = t0 - 2.0f * a;        // fl(fl(sumx+norm) - 2*dot)
            if (dist < best) { best = dist; bi = k; }
        }
        // lexicographic (value, index) min across 64 lanes = first-index argmin
        for (int mask = 32; mask; mask >>= 1) {
            float ov = __shfl_xor(best, mask, 64);
            int   oi = __shfl_xor(bi,   mask, 64);
            if (ov < best || (ov == best && oi < bi)) { best = ov; bi = oi; }
        }
        if (lane == 0) idx[row] = bi;          // clears flag bit
    }
}

// ------------------------------------------------------------------
// 2: gather + straight-through + per-BLOCK loss partial (UNCHANGED, verified)
__global__ __launch_bounds__(256) void vq_gather(const float* __restrict__ x,
                                                 const float* __restrict__ eT,
                                                 const int* __restrict__ idx,
                                                 float* __restrict__ out,
                                                 double* __restrict__ partials) {
#pragma clang fp contract(off)
    __shared__ float wsum[4];
    const int t   = blockIdx.x * 256 + threadIdx.x;   // NROWS*16 threads
    const int row = t >> 4;
    const int j   = t & 15;
    const int k   = idx[row];
    float4 q  = ((const float4*)eT)[(k << 4) + j];
    float4 xv = ((const float4*)x)[t];
    float dx = q.x - xv.x, dy = q.y - xv.y, dz = q.z - xv.z, dw = q.w - xv.w;
    float4 o;
    o.x = xv.x + dx; o.y = xv.y + dy; o.z = xv.z + dz; o.w = xv.w + dw;
    ((float4*)out)[t] = o;
    float s = dx*dx + dy*dy + dz*dz + dw*dw;
#pragma unroll
    for (int off = 32; off > 0; off >>= 1) s += __shfl_down(s, off, 64);
    if ((threadIdx.x & 63) == 0) wsum[threadIdx.x >> 6] = s;
    __syncthreads();
    if (threadIdx.x == 0) {
        double b = (double)wsum[0] + (double)wsum[1]
                 + (double)wsum[2] + (double)wsum[3];
        partials[blockIdx.x] = b;
    }
}

// ------------------------------------------------------------------
// 3: reduce block partials; loss = 1.25 * mse (UNCHANGED, verified)
__global__ __launch_bounds__(256) void vq_finalize(const double* __restrict__ partials,
                                                   float* __restrict__ out_loss) {
    __shared__ double sd[256];
    double a = 0.0;
    for (int i = threadIdx.x; i < GATHER_BLOCKS; i += 256) a += partials[i];
    sd[threadIdx.x] = a;
    __syncthreads();
    for (int s = 128; s > 0; s >>= 1) {
        if (threadIdx.x < s) sd[threadIdx.x] += sd[threadIdx.x + s];
        __syncthreads();
    }
    if (threadIdx.x == 0) {
        double mse = sd[0] / (double)((size_t)NROWS * DDIM);
        *out_loss = (float)(1.25 * mse);
    }
}

// ------------------------------------------------------------------
extern "C" void kernel_launch(void* const* d_in, const int* in_sizes, int n_in,
                              void* d_out, int out_size, void* d_ws, size_t ws_size,
                              hipStream_t stream) {
    const float* x = (const float*)d_in[0];        // [N, 64]
    const float* e = (const float*)d_in[1];        // [64, 1024]
    float* out = (float*)d_out;                    // [N*64 quantized_st] + [1 loss]

    char* ws = (char*)d_ws;
    float*          eT       = (float*)(ws + 0);
    float*          norms    = (float*)(ws + 262144);
    unsigned short* eh       = (unsigned short*)(ws + 266240);
    unsigned short* el       = (unsigned short*)(ws + 397312);
    int*            idx      = (int*)(ws + 528384);
    double*         partials = (double*)(ws + 1576960);

    const size_t CNT_OFF  = 1708032;
    const size_t LIST_OFF = 1709056;
    const size_t REQUIRED = LIST_OFF + (size_t)NROWS * 4;   // ~2.63 MiB
    const bool compact = (ws_size >= REQUIRED);
    int* cnt  = compact ? (int*)(ws + CNT_OFF)  : (int*)0;
    int* list = compact ? (int*)(ws + LIST_OFF) : (int*)0;

    vq_prep    <<<KCODE / 256,   256, 0, stream>>>(e, eT, norms, eh, el, cnt);
    vq_filter  <<<NROWS / 256,   256, 0, stream>>>(x, eh, el, norms, idx, cnt, list);
    if (compact)
        vq_rescore_b<<<2048,     256, 0, stream>>>(x, e, norms, idx, cnt, list);
    else
        vq_rescore  <<<NROWS/16, 256, 0, stream>>>(x, eT, norms, idx);
    vq_gather  <<<GATHER_BLOCKS, 256, 0, stream>>>(x, eT, idx, out, partials);
    vq_finalize<<<1,             256, 0, stream>>>(partials, out + (size_t)NROWS * DDIM);
}

// Round 4
// 300.986 us; speedup vs baseline: 3.2082x; 1.2769x over previous
//
#include <hip/hip_runtime.h>

#define NROWS 262144   // 256*32*32
#define DDIM  64
#define KCODE 1024
#define GATHER_BLOCKS ((NROWS * 16) / 256)   // 16384
#define WINDOW 4e-3f   // certified: worst-case |approx_s - numpy_s| < 1.6e-3; 2.5x margin

// ---- ws layout (bytes) ----
// [0)        eT       float[KCODE*DDIM]   = 262144 B  (codebook transposed, [k][d])
// [262144)   norms    float[KCODE]        = 4096 B    (numpy-order sum of squares)
// [266240)   ph       ushort[64*2*64*8]   = 131072 B  (bf16 hi, MFMA-fragment-packed)
// [397312)   pl       ushort[64*2*64*8]   = 131072 B  (bf16 lo, MFMA-fragment-packed)
// [528384)   idx      int[NROWS]          = 1 MiB     (bit31 = needs exact rescore)
// [1576960)  partials double[16384]       = 128 KiB
// [1708032)  cnt      int                 (compact-list counter, zeroed by vq_prep)
// [1709056)  list     int[NROWS]          = 1 MiB     (compacted flagged-row worklist)
//
// Fragment pack layout (round-4): ph/pl[(tile*2 + s)*512 + lane*8 + j] holds the
// bf16 hi/lo of dim d = (lane>>4)*8 + s*32 + j of code k = tile*16 + (lane&15).
// This is EXACTLY the bf16x8 lane fragment vq_filter consumes, so each of the 4
// B-loads per tile is 64 lanes x contiguous 16 B = one coalesced 1 KiB
// transaction. (Round-3 counters: code-major layout scattered each load over
// ~64 cache lines -> vq_filter was VMEM-divergence bound at 253 us, 2360 cy/tile
// vs ~350 cy issue floor, MfmaUtil+VALUBusy only 44%.)
//
// SEMANTICS (verified bit-exact, absmax 0.0): oracle = numpy fp32,
// AVX512 pairwise sumsq, sequential-d fp32-FMA dot, dist = fl(fl(sumx+norm)-2dot),
// first-index argmin, out = fl(x + fl(q-x)). Exact path preserved in vq_prep /
// vq_rescore* / vq_gather. vq_filter is an APPROXIMATE pass with a certified
// error window; near-ties are rescored exactly. The pack is a pure permutation
// of the same bf16 values; filter math is op-for-op identical (m2 via med3 is
// provably the same value given the m1<=m2 invariant).
//
// RESCORE HISTORY (counter-verified):
//  r0: one wave/row over sparse flags, eT[k][d] reads: 305 us (latency-bound).
//  r1: 4-chain ILP in one lane -> VGPR 256, 1.8 GB scratch spill, 626 us. BAD.
//  r2: compact worklist + e[d][k] reads, single chain: 348 us (load-serialized).
//  r3: vq_rescore_b block-per-4-rows, 16-way ILP: off the top-5 (<40 us). GOOD.

typedef short bf16x8 __attribute__((ext_vector_type(8)));
typedef float f32x4  __attribute__((ext_vector_type(4)));

__device__ __forceinline__ unsigned short bf16_rne(float f) {
    unsigned u = __float_as_uint(f);
    unsigned r = u + 0x7fffu + ((u >> 16) & 1u);
    return (unsigned short)(r >> 16);
}

// ------------------------------------------------------------------
// P: transpose codebook, numpy-order norms, fragment-packed bf16 hi/lo splits,
// zero worklist cnt
__global__ __launch_bounds__(256) void vq_prep(const float* __restrict__ e,
                                               float* __restrict__ eT,
                                               float* __restrict__ norms,
                                               unsigned short* __restrict__ ph,
                                               unsigned short* __restrict__ pl,
                                               int* cnt) {
#pragma clang fp contract(off)
    if (cnt && blockIdx.x == 0 && threadIdx.x == 0) *cnt = 0;
    const int k = blockIdx.x * 256 + threadIdx.x;   // 4 blocks x 256 = 1024
    const int tile = k >> 4;
    const int m    = k & 15;
    float acc = 0.0f;
    for (int d = 0; d < DDIM; ++d) {
        float v = e[d * KCODE + k];      // e is [D][K]; coalesced across k-lanes
        eT[(k << 6) + d] = v;
        unsigned short h = bf16_rne(v);
        float hf = __uint_as_float((unsigned)h << 16);
        // fragment-packed: (tile*2 + s)*512 + (q*16 + m)*8 + j
        const int s = d >> 5, q = (d & 31) >> 3, j = d & 7;
        const int pidx = (((tile << 1) + s) << 9) + ((q << 4) + m) * 8 + j;
        ph[pidx] = h;
        pl[pidx] = bf16_rne(v - hf);     // Sterbenz: v-hf exact
        float sq = v * v;                // rounded square (numpy elementwise mul)
        acc = acc + sq;                  // sequential adds (numpy axis-0 reduce)
    }
    norms[k] = acc;
}

// ------------------------------------------------------------------
// numpy AVX512 pairwise sum of fl(x_d^2) — exact op order, do not touch
__device__ __forceinline__ float numpy_sumsq(const float* xr) {
#pragma clang fp contract(off)
    float u[16];
#pragma unroll
    for (int j = 0; j < 16; ++j) {
        float p0 = xr[j     ] * xr[j     ];
        float p1 = xr[j + 16] * xr[j + 16];
        float p2 = xr[j + 32] * xr[j + 32];
        float p3 = xr[j + 48] * xr[j + 48];
        u[j] = (p0 + p1) + (p2 + p3);
    }
    float v8[8];
#pragma unroll
    for (int j = 0; j < 8; ++j) v8[j] = u[j] + u[j + 8];
    float w4[4];
#pragma unroll
    for (int j = 0; j < 4; ++j) w4[j] = v8[j] + v8[j + 4];
    float y0 = w4[0] + w4[2];
    float y1 = w4[1] + w4[3];
    return y0 + y1;
}

// ------------------------------------------------------------------
// 1: MFMA split-bf16 approximate argmin. Wave = 64 rows x 1024 codes.
// s_k = norm_k - 2*dot_k (sumx is row-constant, irrelevant for argmin).
// Flags rows whose top-2 gap <= WINDOW for exact rescore (idx bit 31),
// and appends flagged rows to the compact worklist (ONE atomic per wave).
__global__ __launch_bounds__(256, 2) void vq_filter(const float* __restrict__ x,
                                                    const unsigned short* __restrict__ ph,
                                                    const unsigned short* __restrict__ pl,
                                                    const float* __restrict__ norms,
                                                    int* __restrict__ idx,
                                                    int* cnt,
                                                    int* list) {
    const int lane = threadIdx.x & 63;
    const int wave = threadIdx.x >> 6;
    const int wavebase = blockIdx.x * 256 + wave * 64;   // 64 rows per wave
    const int m    = lane & 15;       // A-row within 16 / C-col (code) within 16
    const int quad = lane >> 4;       // k-chunk selector / C-row group

    // ---- build A fragments (hi/lo), 4 row-groups x 2 K-steps ----
    // A layout (verified m120): A[m=lane&15][k=quad*8+j]
    bf16x8 ah[4][2], al[4][2];
#pragma unroll
    for (int g = 0; g < 4; ++g) {
        const float* xp = x + (size_t)(wavebase + g * 16 + m) * DDIM + quad * 8;
#pragma unroll
        for (int s = 0; s < 2; ++s) {
            float4 v0 = *(const float4*)(xp + s * 32);
            float4 v1 = *(const float4*)(xp + s * 32 + 4);
            float f[8] = {v0.x, v0.y, v0.z, v0.w, v1.x, v1.y, v1.z, v1.w};
#pragma unroll
            for (int j = 0; j < 8; ++j) {
                unsigned short h = bf16_rne(f[j]);
                float hf = __uint_as_float((unsigned)h << 16);
                ah[g][s][j] = (short)h;
                al[g][s][j] = (short)bf16_rne(f[j] - hf);
            }
        }
    }

    // ---- per-lane running (min1, min2, argmin) for 4 groups x 4 C-rows ----
    float m1[4][4], m2[4][4];
    int   id[4][4];
#pragma unroll
    for (int g = 0; g < 4; ++g)
#pragma unroll
        for (int r = 0; r < 4; ++r) { m1[g][r] = 3.4e38f; m2[g][r] = 3.4e38f; id[g][r] = 0; }

    // fragment-packed B: one bf16x8 per lane per (tile, s) — fully coalesced
    const bf16x8* __restrict__ phv = (const bf16x8*)ph;
    const bf16x8* __restrict__ plv = (const bf16x8*)pl;

    for (int tile = 0; tile < KCODE / 16; ++tile) {
        const int code = tile * 16 + m;
        const int fb = (tile << 7) + lane;    // (tile*2+0)*64 + lane
        bf16x8 bh0 = phv[fb];
        bf16x8 bh1 = phv[fb + 64];
        bf16x8 bl0 = plv[fb];
        bf16x8 bl1 = plv[fb + 64];
        float nrm = norms[code];
#pragma unroll
        for (int g = 0; g < 4; ++g) {
            f32x4 acc = {0.f, 0.f, 0.f, 0.f};
            acc = __builtin_amdgcn_mfma_f32_16x16x32_bf16(ah[g][0], bh0, acc, 0, 0, 0);
            acc = __builtin_amdgcn_mfma_f32_16x16x32_bf16(ah[g][1], bh1, acc, 0, 0, 0);
            acc = __builtin_amdgcn_mfma_f32_16x16x32_bf16(ah[g][0], bl0, acc, 0, 0, 0);
            acc = __builtin_amdgcn_mfma_f32_16x16x32_bf16(ah[g][1], bl1, acc, 0, 0, 0);
            acc = __builtin_amdgcn_mfma_f32_16x16x32_bf16(al[g][0], bh0, acc, 0, 0, 0);
            acc = __builtin_amdgcn_mfma_f32_16x16x32_bf16(al[g][1], bh1, acc, 0, 0, 0);
            // C layout (verified m89/m91): col=lane&15 (code), row=quad*4+reg
#pragma unroll
            for (int r = 0; r < 4; ++r) {
                float sv = fmaf(-2.0f, acc[r], nrm);
                // m2' = median(m1, m2, sv) == (sv<m1 ? m1 : min(m2,sv)) given m1<=m2
                m2[g][r] = __builtin_amdgcn_fmed3f(m1[g][r], m2[g][r], sv);
                bool lt = sv < m1[g][r];
                m1[g][r] = lt ? sv : m1[g][r];
                id[g][r] = lt ? code : id[g][r];
            }
        }
    }

    // ---- cross-lane merge over the 16 code-columns (lanes sharing quad) ----
#pragma unroll
    for (int g = 0; g < 4; ++g)
#pragma unroll
        for (int r = 0; r < 4; ++r) {
            float a1 = m1[g][r], a2 = m2[g][r];
            int   ai = id[g][r];
            for (int mask = 1; mask < 16; mask <<= 1) {
                float o1 = __shfl_xor(a1, mask, 64);
                float o2 = __shfl_xor(a2, mask, 64);
                int   oi = __shfl_xor(ai, mask, 64);
                float n2 = fminf(fminf(a2, o2), fmaxf(a1, o1));
                bool take = o1 < a1;
                a1 = take ? o1 : a1;
                ai = take ? oi : ai;
                a2 = n2;
            }
            m1[g][r] = a1; m2[g][r] = a2; id[g][r] = ai;
        }

    // After the merge, m1/m2/id are uniform across the 16 lanes of each quad,
    // so EVERY lane can compute its quad's flag count (no divergence here).
    int nf = 0;
#pragma unroll
    for (int g = 0; g < 4; ++g)
#pragma unroll
        for (int r = 0; r < 4; ++r)
            nf += ((m2[g][r] - m1[g][r]) <= WINDOW) ? 1 : 0;

    // wave-aggregated worklist append: ONE atomic per wave
    int myoff = 0;
    if (list) {
        int nf0 = __shfl(nf, 0, 64);
        int nf1 = __shfl(nf, 16, 64);
        int nf2 = __shfl(nf, 32, 64);
        int nf3 = __shfl(nf, 48, 64);
        int wtotal = nf0 + nf1 + nf2 + nf3;
        int wbase = 0;
        if (lane == 0 && wtotal) wbase = atomicAdd(cnt, wtotal);
        wbase = __shfl(wbase, 0, 64);
        myoff = wbase + (quad > 0 ? nf0 : 0) + (quad > 1 ? nf1 : 0)
                      + (quad > 2 ? nf2 : 0);
    }

    if (m == 0) {
#pragma unroll
        for (int g = 0; g < 4; ++g)
#pragma unroll
            for (int r = 0; r < 4; ++r) {
                int row = wavebase + g * 16 + quad * 4 + r;
                bool flag = (m2[g][r] - m1[g][r]) <= WINDOW;
                idx[row] = flag ? (id[g][r] | 0x80000000) : id[g][r];
                if (list && flag) list[myoff++] = row;
            }
    }
}

// ------------------------------------------------------------------
// Rb: exact numpy rescore, one BLOCK per group of 4 worklist rows.
// Thread t owns codes k = 4t..4t+3 (ascending within thread; lexicographic
// (value,index) reduction across threads => global first-index argmin).
// Per d-step: one dwordx4 load of e[d][4t..4t+3] (wave reads a contiguous
// 1 KiB slice -> fully coalesced) + LDS broadcast of xs[r][d] + 16 chained
// FMAs (4 rows x 4 codes, independent chains -> issue-bound, latency hidden).
// Each chain's op order is IDENTICAL to vq_rescore: bit-exact.
__global__ __launch_bounds__(256) void vq_rescore_b(const float* __restrict__ x,
                                                    const float* __restrict__ e,   // [D][K]
                                                    const float* __restrict__ norms,
                                                    int* __restrict__ idx,
                                                    const int* __restrict__ cnt,
                                                    const int* __restrict__ list) {
#pragma clang fp contract(off)
    __shared__ float xs[4][DDIM];     // 4 staged rows
    __shared__ float sumxs[4];
    __shared__ int   rows_s[4];
    __shared__ float wval[4][4];      // [row][wave] lex-reduce partials
    __shared__ int   widx[4][4];

    const int tid  = threadIdx.x;
    const int lane = tid & 63;
    const int wave = tid >> 6;
    const int total = *cnt;
    const int ngroups = (total + 3) >> 2;

    const float* ep = e + (tid << 2);                       // e[0][4t]
    const float4 nv = *(const float4*)(norms + (tid << 2)); // norms[4t..4t+3]

    for (int g = blockIdx.x; g < ngroups; g += gridDim.x) {
        const int base = g * 4;
        const int nr = min(4, total - base);

        // ---- stage 4 rows into LDS (64 threads per row, stride-1: no conflicts)
        {
            int r = wave;            // tid>>6: one wave per row
            int d = lane;
            int row = (r < nr) ? list[base + r] : list[base];  // pad with row 0
            if (d == 0) rows_s[r] = row;
            xs[r][d] = x[(size_t)row * DDIM + d];
        }
        __syncthreads();

        // ---- sumsq per row: wave r computes row r with a bit-exact 16-lane tree.
        // u[j] on lane j (j<16); each xor level adds self+other, reproducing
        // numpy's pairwise order exactly (IEEE add is bitwise commutative).
        {
            int r = wave;
            float uj = 0.f;
            if (lane < 16) {
                float a0 = xs[r][lane];
                float a1 = xs[r][lane + 16];
                float a2 = xs[r][lane + 32];
                float a3 = xs[r][lane + 48];
                float p0 = a0 * a0, p1 = a1 * a1, p2 = a2 * a2, p3 = a3 * a3;
                uj = (p0 + p1) + (p2 + p3);
            }
            uj = uj + __shfl_xor(uj, 8, 64);   // v8[j] = u[j] + u[j+8]
            uj = uj + __shfl_xor(uj, 4, 64);   // w4[j] = v8[j] + v8[j+4]
            uj = uj + __shfl_xor(uj, 2, 64);   // y0 = w4[0]+w4[2] (lane0)
            uj = uj + __shfl_xor(uj, 1, 64);   // y0+y1 (lane0)
            if (lane == 0) sumxs[r] = uj;
        }
        __syncthreads();

        // ---- 16 independent sequential-d chains: 4 rows x 4 codes ----
        f32x4 a0 = {0.f, 0.f, 0.f, 0.f};
        f32x4 a1 = {0.f, 0.f, 0.f, 0.f};
        f32x4 a2 = {0.f, 0.f, 0.f, 0.f};
        f32x4 a3 = {0.f, 0.f, 0.f, 0.f};
#pragma unroll 8
        for (int d = 0; d < DDIM; ++d) {
            float4 ev = *(const float4*)(ep + (size_t)d * KCODE);
            float x0 = xs[0][d], x1 = xs[1][d], x2 = xs[2][d], x3 = xs[3][d];
            a0.x = fmaf(x0, ev.x, a0.x); a0.y = fmaf(x0, ev.y, a0.y);
            a0.z = fmaf(x0, ev.z, a0.z); a0.w = fmaf(x0, ev.w, a0.w);
            a1.x = fmaf(x1, ev.x, a1.x); a1.y = fmaf(x1, ev.y, a1.y);
            a1.z = fmaf(x1, ev.z, a1.z); a1.w = fmaf(x1, ev.w, a1.w);
            a2.x = fmaf(x2, ev.x, a2.x); a2.y = fmaf(x2, ev.y, a2.y);
            a2.z = fmaf(x2, ev.z, a2.z); a2.w = fmaf(x2, ev.w, a2.w);
            a3.x = fmaf(x3, ev.x, a3.x); a3.y = fmaf(x3, ev.y, a3.y);
            a3.z = fmaf(x3, ev.z, a3.z); a3.w = fmaf(x3, ev.w, a3.w);
        }

        // ---- per-row distances + lexicographic first-index argmin ----
#pragma unroll
        for (int r = 0; r < 4; ++r) {
            f32x4 ar = (r == 0) ? a0 : (r == 1) ? a1 : (r == 2) ? a2 : a3;
            float sx = sumxs[r];
            float bv = 3.4e38f; int bx = 0;
            {   // ascending k within thread: first-index on ties via strict <
                float t0 = sx + nv.x; float d0 = t0 - 2.0f * ar.x;
                if (d0 < bv) { bv = d0; bx = (tid << 2) + 0; }
                float t1 = sx + nv.y; float d1 = t1 - 2.0f * ar.y;
                if (d1 < bv) { bv = d1; bx = (tid << 2) + 1; }
                float t2 = sx + nv.z; float d2 = t2 - 2.0f * ar.z;
                if (d2 < bv) { bv = d2; bx = (tid << 2) + 2; }
                float t3 = sx + nv.w; float d3 = t3 - 2.0f * ar.w;
                if (d3 < bv) { bv = d3; bx = (tid << 2) + 3; }
            }
            for (int mask = 32; mask; mask >>= 1) {
                float ov = __shfl_xor(bv, mask, 64);
                int   ox = __shfl_xor(bx, mask, 64);
                if (ov < bv || (ov == bv && ox < bx)) { bv = ov; bx = ox; }
            }
            if (lane == 0) { wval[r][wave] = bv; widx[r][wave] = bx; }
        }
        __syncthreads();

        if (tid < nr) {
            float bv = wval[tid][0]; int bx = widx[tid][0];
#pragma unroll
            for (int w = 1; w < 4; ++w) {
                float ov = wval[tid][w]; int ox = widx[tid][w];
                if (ov < bv || (ov == bv && ox < bx)) { bv = ov; bx = ox; }
            }
            idx[rows_s[tid]] = bx;    // clears flag bit
        }
        __syncthreads();   // protect xs/rows_s/wval before next group
    }
}

// ------------------------------------------------------------------
// R (fallback, only if ws too small for the worklist): exact numpy rescore
// of flagged rows. One wave per row. UNCHANGED from verified version.
__global__ __launch_bounds__(256) void vq_rescore(const float* __restrict__ x,
                                                  const float* __restrict__ eT,
                                                  const float* __restrict__ norms,
                                                  int* __restrict__ idx) {
#pragma clang fp contract(off)
    const int wave = threadIdx.x >> 6;
    const int lane = threadIdx.x & 63;
    const int rowbase = blockIdx.x * 16 + wave * 4;   // 16384 blocks x 16 rows
    for (int i = 0; i < 4; ++i) {
        const int row = rowbase + i;
        if (idx[row] >= 0) continue;           // uniform branch (broadcast load)
        float xr[DDIM];
        const float4* xv = (const float4*)(x + (size_t)row * DDIM);
#pragma unroll
        for (int t = 0; t < DDIM / 4; ++t) {
            float4 v = xv[t];
            xr[4*t+0] = v.x; xr[4*t+1] = v.y; xr[4*t+2] = v.z; xr[4*t+3] = v.w;
        }
        float sumx = numpy_sumsq(xr);
        float best = 3.4e38f; int bi = 0;
        for (int j = 0; j < 16; ++j) {
            const int k = j * 64 + lane;       // ascending k per lane
            const float* __restrict__ ek = eT + (k << 6);
            float a = 0.f;
#pragma unroll
            for (int d = 0; d < DDIM; ++d)
                a = fmaf(xr[d], ek[d], a);     // strict sequential d-chain
            float t0 = sumx + norms[k];
            float dist = t0 - 2.0f * a;        // fl(fl(sumx+norm) - 2*dot)
            if (dist < best) { best = dist; bi = k; }
        }
        // lexicographic (value, index) min across 64 lanes = first-index argmin
        for (int mask = 32; mask; mask >>= 1) {
            float ov = __shfl_xor(best, mask, 64);
            int   oi = __shfl_xor(bi,   mask, 64);
            if (ov < best || (ov == best && oi < bi)) { best = ov; bi = oi; }
        }
        if (lane == 0) idx[row] = bi;          // clears flag bit
    }
}

// ------------------------------------------------------------------
// 2: gather + straight-through + per-BLOCK loss partial (UNCHANGED, verified)
__global__ __launch_bounds__(256) void vq_gather(const float* __restrict__ x,
                                                 const float* __restrict__ eT,
                                                 const int* __restrict__ idx,
                                                 float* __restrict__ out,
                                                 double* __restrict__ partials) {
#pragma clang fp contract(off)
    __shared__ float wsum[4];
    const int t   = blockIdx.x * 256 + threadIdx.x;   // NROWS*16 threads
    const int row = t >> 4;
    const int j   = t & 15;
    const int k   = idx[row];
    float4 q  = ((const float4*)eT)[(k << 4) + j];
    float4 xv = ((const float4*)x)[t];
    float dx = q.x - xv.x, dy = q.y - xv.y, dz = q.z - xv.z, dw = q.w - xv.w;
    float4 o;
    o.x = xv.x + dx; o.y = xv.y + dy; o.z = xv.z + dz; o.w = xv.w + dw;
    ((float4*)out)[t] = o;
    float s = dx*dx + dy*dy + dz*dz + dw*dw;
#pragma unroll
    for (int off = 32; off > 0; off >>= 1) s += __shfl_down(s, off, 64);
    if ((threadIdx.x & 63) == 0) wsum[threadIdx.x >> 6] = s;
    __syncthreads();
    if (threadIdx.x == 0) {
        double b = (double)wsum[0] + (double)wsum[1]
                 + (double)wsum[2] + (double)wsum[3];
        partials[blockIdx.x] = b;
    }
}

// ------------------------------------------------------------------
// 3: reduce block partials; loss = 1.25 * mse (UNCHANGED, verified)
__global__ __launch_bounds__(256) void vq_finalize(const double* __restrict__ partials,
                                                   float* __restrict__ out_loss) {
    __shared__ double sd[256];
    double a = 0.0;
    for (int i = threadIdx.x; i < GATHER_BLOCKS; i += 256) a += partials[i];
    sd[threadIdx.x] = a;
    __syncthreads();
    for (int s = 128; s > 0; s >>= 1) {
        if (threadIdx.x < s) sd[threadIdx.x] += sd[threadIdx.x + s];
        __syncthreads();
    }
    if (threadIdx.x == 0) {
        double mse = sd[0] / (double)((size_t)NROWS * DDIM);
        *out_loss = (float)(1.25 * mse);
    }
}

// ------------------------------------------------------------------
extern "C" void kernel_launch(void* const* d_in, const int* in_sizes, int n_in,
                              void* d_out, int out_size, void* d_ws, size_t ws_size,
                              hipStream_t stream) {
    const float* x = (const float*)d_in[0];        // [N, 64]
    const float* e = (const float*)d_in[1];        // [64, 1024]
    float* out = (float*)d_out;                    // [N*64 quantized_st] + [1 loss]

    char* ws = (char*)d_ws;
    float*          eT       = (float*)(ws + 0);
    float*          norms    = (float*)(ws + 262144);
    unsigned short* ph       = (unsigned short*)(ws + 266240);
    unsigned short* pl       = (unsigned short*)(ws + 397312);
    int*            idx      = (int*)(ws + 528384);
    double*         partials = (double*)(ws + 1576960);

    const size_t CNT_OFF  = 1708032;
    const size_t LIST_OFF = 1709056;
    const size_t REQUIRED = LIST_OFF + (size_t)NROWS * 4;   // ~2.63 MiB
    const bool compact = (ws_size >= REQUIRED);
    int* cnt  = compact ? (int*)(ws + CNT_OFF)  : (int*)0;
    int* list = compact ? (int*)(ws + LIST_OFF) : (int*)0;

    vq_prep    <<<KCODE / 256,   256, 0, stream>>>(e, eT, norms, ph, pl, cnt);
    vq_filter  <<<NROWS / 256,   256, 0, stream>>>(x, ph, pl, norms, idx, cnt, list);
    if (compact)
        vq_rescore_b<<<2048,     256, 0, stream>>>(x, e, norms, idx, cnt, list);
    else
        vq_rescore  <<<NROWS/16, 256, 0, stream>>>(x, eT, norms, idx);
    vq_gather  <<<GATHER_BLOCKS, 256, 0, stream>>>(x, eT, idx, out, partials);
    vq_finalize<<<1,             256, 0, stream>>>(partials, out + (size_t)NROWS * DDIM);
}